// Round 4
// baseline (37063.580 us; speedup 1.0000x reference)
//
#include <hip/hip_runtime.h>

// BI-LSTM (TF LSTMCell w/ projection), T=160 B=640 F=40 HID=768 PROJ=256, 3 layers x 2 dirs.
// R9: PERSISTENT kernel. R6/R8 evidence: kernel bodies ~15-20us/step but step costs 36.3us
// -> ~16-20us/step of serial launch overhead (324 dependent launches). Replace the 162x2
// launch loop with ONE kernel that loops s=0..161 internally, separated by a hand-rolled
// sense-reversing grid barrier (device-scope fence = same L2 wb+inv a kernel boundary pays,
// but no dispatch/ramp/drain latency).
// Deadlock safety (the R7 lesson): grid = 720 blocks EXACTLY = gate tile count, and
// __launch_bounds__(256,3) caps VGPR<=168 with LDS 3x36.9KB<=160KB -> 3 blocks/CU
// guaranteed -> 768 slots >= 720: ALL blocks co-resident, barrier always makes progress.
// Blocks are CU-pinned across steps (c-state affinity); refetch after each barrier runs
// with full 720-block parallelism (BW-bound, not R7's 240-block latency-bound tail).
// Phase map per step: all 720 blocks gate (24nx5mx6z of 128x128) | barrier |
// blocks 0..239 proj (4nx10mx6z of 64x64) | barrier.

typedef _Float16 h8 __attribute__((ext_vector_type(8)));
typedef float f4 __attribute__((ext_vector_type(4)));

#define T_STEPS 160
#define NB 640
#define HID 768
#define PROJ 256
#define NGATE 3072           // 4*HID
#define SL ((size_t)NB * PROJ)

__device__ __forceinline__ float sigm(float x) { return 1.0f / (1.0f + __expf(-x)); }
__device__ __forceinline__ float tanh_fast(float x) { return 2.0f / (1.0f + __expf(-2.0f * x)) - 1.0f; }

struct PArgs {
  const _Float16* X16;
  const _Float16* Wk[6];     // WkT, gate-interleaved [3072][Kpad], z = l*2+d
  const float*    bias[6];
  const _Float16* Wp[6];     // [256][768] fp16 (B^T)
  _Float16* Hbuf;            // [z][4 slots][640][256]
  float*    cst;             // [z][640][768]
  _Float16* gbuf;            // [z][640][768]
  _Float16* embed;           // [d][which][640][256]
  int* bar;                  // bar[0]=cnt, bar[32]=gen (separate cachelines)
};

// sense-reversing grid barrier, 720 blocks. threadfence = device-scope release (wb L2);
// trailing acquire load invalidates this XCD's caches before consumer reads.
__device__ __forceinline__ void gridbar(int* bar) {
  __threadfence();
  __syncthreads();
  if (threadIdx.x == 0) {
    int* cnt = bar;
    int* gen = bar + 32;
    int g = __hip_atomic_load(gen, __ATOMIC_RELAXED, __HIP_MEMORY_SCOPE_AGENT);
    int a = __hip_atomic_fetch_add(cnt, 1, __ATOMIC_ACQ_REL, __HIP_MEMORY_SCOPE_AGENT);
    if (a == 719) {
      __hip_atomic_store(cnt, 0, __ATOMIC_RELAXED, __HIP_MEMORY_SCOPE_AGENT);
      __hip_atomic_store(gen, g + 1, __ATOMIC_RELEASE, __HIP_MEMORY_SCOPE_AGENT);
    } else {
      while (__hip_atomic_load(gen, __ATOMIC_RELAXED, __HIP_MEMORY_SCOPE_AGENT) == g)
        __builtin_amdgcn_s_sleep(2);
    }
    (void)__hip_atomic_load(gen, __ATOMIC_ACQUIRE, __HIP_MEMORY_SCOPE_AGENT);
  }
  __syncthreads();
}

// ---------------- gate GEMM: z = [x,h] @ WkT^T, fused bias+gates+c-update -> g ----------------
__device__ __forceinline__ void gate_body(char* sm, const _Float16* A0, const _Float16* A1,
                                          const _Float16* Bw, const float* bias,
                                          float* cstate, _Float16* gout,
                                          int w0, int lda0, int K, int n0, int m0, int tid) {
  _Float16 (*As)[72] = (_Float16(*)[72])sm;      // [128][72]
  _Float16 (*Bs)[72] = (_Float16(*)[72])(sm + 18432);
  float (*zs)[65] = (float(*)[65])sm;            // [128][65] f32 (epilogue overlay)

  const int lane = tid & 63;
  const int wv = tid >> 6;         // 0..3
  const int wm = (wv & 1) * 64;    // wave covers rows [wm, wm+64), cols [wn, wn+64)
  const int wn = (wv >> 1) * 64;

  // epilogue-operand prefetch (addresses known up-front; latency hides under MFMAs)
  const int uu = tid & 15;
  const int rbase = tid >> 4;
  float cpre[2][8];
  float bpre[2][4];
#pragma unroll
  for (int p = 0; p < 2; ++p) {
    const int u0 = (n0 + p * 64) >> 2;
#pragma unroll
    for (int gg = 0; gg < 4; ++gg)
      bpre[p][gg] = bias[gg * HID + u0 + uu];
#pragma unroll
    for (int it = 0; it < 8; ++it)
      cpre[p][it] = cstate[(size_t)(m0 + it * 16 + rbase) * HID + u0 + uu];
  }

  f4 acc[4][4] = {};

  const int lr = tid >> 3;          // 0..31 (handles rows lr + 32*r)
  const int lkg = (tid & 7) * 8;    // k-group 0,8,..,56

  for (int k0 = 0; k0 < K; k0 += 64) {
    const int gk = k0 + lkg;
    h8 av[4], bv[4];
    if (gk < w0) {
#pragma unroll
      for (int r = 0; r < 4; ++r)
        av[r] = *(const h8*)(A0 + (size_t)(m0 + lr + 32 * r) * lda0 + gk);
    } else {
#pragma unroll
      for (int r = 0; r < 4; ++r)
        av[r] = *(const h8*)(A1 + (size_t)(m0 + lr + 32 * r) * 256 + (gk - w0));
    }
#pragma unroll
    for (int r = 0; r < 4; ++r)
      bv[r] = *(const h8*)(Bw + (size_t)(n0 + lr + 32 * r) * K + gk);
    __syncthreads();                 // prior iter's frag reads complete
#pragma unroll
    for (int r = 0; r < 4; ++r) {
      *(h8*)&As[lr + 32 * r][lkg] = av[r];
      *(h8*)&Bs[lr + 32 * r][lkg] = bv[r];
    }
    __syncthreads();
#pragma unroll
    for (int kk = 0; kk < 2; ++kk) {
      const int kq = ((lane >> 4) * 8) + kk * 32;
      h8 bf[4];
#pragma unroll
      for (int j = 0; j < 4; ++j)
        bf[j] = *(const h8*)&Bs[wn + (lane & 15) + 16 * j][kq];
#pragma unroll
      for (int i = 0; i < 4; ++i) {
        h8 af = *(const h8*)&As[wm + (lane & 15) + 16 * i][kq];
#pragma unroll
        for (int j = 0; j < 4; ++j)
          acc[i][j] = __builtin_amdgcn_mfma_f32_16x16x32_f16(af, bf[j], acc[i][j], 0, 0, 0);
      }
    }
  }

  // epilogue: two 64-col passes through zs (16 hidden units each)
#pragma unroll
  for (int p = 0; p < 2; ++p) {
    __syncthreads();
    if ((wv >> 1) == p) {                   // waves owning n-half p write their acc
#pragma unroll
      for (int mi = 0; mi < 4; ++mi)
#pragma unroll
        for (int ni = 0; ni < 4; ++ni)
#pragma unroll
          for (int r = 0; r < 4; ++r) {
            int row = wm + mi * 16 + ((lane >> 4) << 2) + r;  // C/D: row=(lane>>4)*4+reg
            int col = ni * 16 + (lane & 15);                  //      col=lane&15 (0..63)
            zs[row][col] = acc[mi][ni][r];
          }
    }
    __syncthreads();
    const int u0 = (n0 + p * 64) >> 2;      // first hidden unit of this pass
#pragma unroll
    for (int it = 0; it < 8; ++it) {
      int row = it * 16 + rbase;            // 128 rows x 16 units
      float zi = zs[row][4 * uu + 0] + bpre[p][0];
      float zj = zs[row][4 * uu + 1] + bpre[p][1];
      float zf = zs[row][4 * uu + 2] + bpre[p][2];
      float zo = zs[row][4 * uu + 3] + bpre[p][3];
      size_t co = (size_t)(m0 + row) * HID + u0 + uu;
      float cold = cpre[p][it];
      float cnew = sigm(zf + 1.0f) * cold + sigm(zi) * tanh_fast(zj);  // forget_bias=1.0
      float g = sigm(zo) * tanh_fast(cnew);
      cstate[co] = cnew;
      gout[co] = (_Float16)g;
    }
  }
}

// ---------------- projection GEMM: h = g @ WpT^T (64x64 tile, K=768) ----------------
__device__ __forceinline__ void proj_body(char* sm, const _Float16* A, const _Float16* B,
                                          _Float16* outp, _Float16* out2,
                                          int n0, int m0, int tid) {
  _Float16 (*As)[72] = (_Float16(*)[72])sm;             // [64][72]
  _Float16 (*Bs)[72] = (_Float16(*)[72])(sm + 9216);

  const int lane = tid & 63;
  const int wv = tid >> 6;
  const int wm = (wv & 1) * 32;
  const int wn = (wv >> 1) * 32;

  f4 acc[2][2] = {};
  const int lr = tid >> 3;
  const int lkg = (tid & 7) * 8;

  for (int k0 = 0; k0 < HID; k0 += 64) {
    const int gk = k0 + lkg;
    h8 av0 = *(const h8*)(A + (size_t)(m0 + lr) * HID + gk);
    h8 av1 = *(const h8*)(A + (size_t)(m0 + lr + 32) * HID + gk);
    h8 bv0 = *(const h8*)(B + (size_t)(n0 + lr) * HID + gk);
    h8 bv1 = *(const h8*)(B + (size_t)(n0 + lr + 32) * HID + gk);
    __syncthreads();
    *(h8*)&As[lr][lkg] = av0;
    *(h8*)&As[lr + 32][lkg] = av1;
    *(h8*)&Bs[lr][lkg] = bv0;
    *(h8*)&Bs[lr + 32][lkg] = bv1;
    __syncthreads();
    const int mr = wm + (lane & 15);
    const int nr = wn + (lane & 15);
#pragma unroll
    for (int kk = 0; kk < 2; ++kk) {
      const int kq = ((lane >> 4) * 8) + kk * 32;
      h8 a0 = *(const h8*)&As[mr][kq];
      h8 a1 = *(const h8*)&As[mr + 16][kq];
      h8 b0 = *(const h8*)&Bs[nr][kq];
      h8 b1 = *(const h8*)&Bs[nr + 16][kq];
      acc[0][0] = __builtin_amdgcn_mfma_f32_16x16x32_f16(a0, b0, acc[0][0], 0, 0, 0);
      acc[0][1] = __builtin_amdgcn_mfma_f32_16x16x32_f16(a0, b1, acc[0][1], 0, 0, 0);
      acc[1][0] = __builtin_amdgcn_mfma_f32_16x16x32_f16(a1, b0, acc[1][0], 0, 0, 0);
      acc[1][1] = __builtin_amdgcn_mfma_f32_16x16x32_f16(a1, b1, acc[1][1], 0, 0, 0);
    }
  }

#pragma unroll
  for (int mi = 0; mi < 2; ++mi)
#pragma unroll
    for (int ni = 0; ni < 2; ++ni)
#pragma unroll
      for (int r = 0; r < 4; ++r) {
        int row = wm + mi * 16 + ((lane >> 4) << 2) + r;
        int col = wn + ni * 16 + (lane & 15);
        _Float16 v = (_Float16)acc[mi][ni][r];
        size_t o = (size_t)(m0 + row) * PROJ + (n0 + col);
        outp[o] = v;
        if (out2) out2[o] = v;
      }
}

// ---------------- the persistent step loop ----------------
__global__ __launch_bounds__(256, 3) void persist(PArgs A) {
  __shared__ __align__(16) char sm[36864];
  const int b = blockIdx.x;
  const int tid = threadIdx.x;

  // gate decomposition (all 720 blocks): z in 0..5, 24 n-tiles x 5 m-tiles
  const int gz = b / 120, grem = b % 120, gbx = grem % 24, gby = grem / 24;
  const int gl = gz >> 1, gd = gz & 1;
  // proj decomposition (blocks 0..239): z in 0..5, 4 n-tiles x 10 m-tiles
  const int pz = b / 40, prem = b % 40, pbx = prem % 4, pby = prem / 4;
  const int pl = pz >> 1, pd = pz & 1;

  for (int s = 0; s <= 161; ++s) {
    // ---- gate phase ----
    {
      const int t = s - gl;
      if (t >= 0 && t <= 159) {
        const int tt = gd ? (159 - t) : t;
        const _Float16* A0;
        int w0, lda0, K;
        if (gl == 0) {
          A0 = A.X16 + (size_t)tt * NB * 64;
          w0 = 64; lda0 = 64; K = 320;
        } else {
          A0 = A.Hbuf + ((size_t)(((gl - 1) * 2 + gd) * 4) + ((tt + 1) & 3)) * SL;
          w0 = 256; lda0 = 256; K = 512;
        }
        const int rds = (gd == 0) ? (tt & 3) : ((tt + 2) & 3);
        const _Float16* A1 = A.Hbuf + ((size_t)(gz * 4) + rds) * SL;
        gate_body(sm, A0, A1, A.Wk[gz], A.bias[gz],
                  A.cst + (size_t)gz * NB * HID, A.gbuf + (size_t)gz * NB * HID,
                  w0, lda0, K, gbx * 128, gby * 128, tid);
      }
    }
    gridbar(A.bar);
    // ---- proj phase ----
    if (b < 240) {
      const int t = s - pl;
      if (t >= 0 && t <= 159) {
        const int tt = pd ? (159 - t) : t;
        _Float16* outp = A.Hbuf + ((size_t)(pz * 4) + ((tt + 1) & 3)) * SL;
        _Float16* out2 = nullptr;
        if (pl == 2 && (tt == 0 || tt == 159))
          out2 = A.embed + ((size_t)pd * 2 + (tt == 0 ? 0 : 1)) * SL;
        proj_body(sm, A.gbuf + (size_t)pz * NB * HID, A.Wp[pz], outp, out2,
                  pbx * 64, pby * 64, tid);
      }
    }
    gridbar(A.bar);
  }
}

// ---------------- prep kernels ----------------
__global__ void convX(const float* __restrict__ X, _Float16* __restrict__ X16, size_t total) {
  size_t i = (size_t)blockIdx.x * 256 + threadIdx.x;
  if (i >= total) return;
  int p = (int)(i & 63);
  size_t tb = i >> 6;
  float v = (p < 40) ? X[tb * 40 + p] : 0.0f;
  X16[i] = (_Float16)v;
}

// Wk fp32 [Kin+256, 3072] -> WkT fp16 [3072][Kpad], gate-interleaved rows n'=4u+g,
// layer0 k-map: k<40 -> Wk[k]; 40..63 -> 0; 64..319 -> Wk[k-24]
__global__ void conv_wk(const float* __restrict__ Wk, _Float16* __restrict__ out,
                        int mode, int Kpad, size_t total) {
  size_t i = (size_t)blockIdx.x * 256 + threadIdx.x;
  if (i >= total) return;
  int k = (int)(i % Kpad);
  int n = (int)(i / Kpad);
  int u = n >> 2, g = n & 3;
  int col = g * HID + u;
  float v;
  if (mode == 0) {
    if (k < 40)      v = Wk[(size_t)k * NGATE + col];
    else if (k < 64) v = 0.0f;
    else             v = Wk[(size_t)(k - 24) * NGATE + col];
  } else {
    v = Wk[(size_t)k * NGATE + col];
  }
  out[i] = (_Float16)v;
}

__global__ void conv_wp(const float* __restrict__ Wp, _Float16* __restrict__ out, size_t total) {
  size_t i = (size_t)blockIdx.x * 256 + threadIdx.x;
  if (i >= total) return;
  int k = (int)(i % HID);
  int c = (int)(i / HID);
  out[i] = (_Float16)Wp[(size_t)k * PROJ + c];
}

// ---------------- readout ----------------
__global__ __launch_bounds__(256) void readout(const _Float16* __restrict__ E, float* __restrict__ out) {
  int b = blockIdx.x, tid = threadIdx.x;
  float v[2];
  float ss = 0.0f;
#pragma unroll
  for (int i = 0; i < 2; ++i) {
    int j = tid + i * 256;
    int d = j >> 8, c = j & 255;
    const _Float16* base = E + (size_t)d * 2 * SL;
    float a = (float)base[(size_t)b * PROJ + c];
    float zv = (float)base[SL + (size_t)b * PROJ + c];
    v[i] = 0.5f * (a + zv);
    ss += v[i] * v[i];
  }
#pragma unroll
  for (int off = 32; off; off >>= 1) ss += __shfl_down(ss, off);
  __shared__ float ps[4];
  if ((tid & 63) == 0) ps[tid >> 6] = ss;
  __syncthreads();
  float tot = ps[0] + ps[1] + ps[2] + ps[3];
  float nrm = rsqrtf(fmaxf(tot, 1e-12f));
  out[(size_t)b * 512 + tid] = v[0] * nrm;
  out[(size_t)b * 512 + tid + 256] = v[1] * nrm;
}

extern "C" void kernel_launch(void* const* d_in, const int* in_sizes, int n_in,
                              void* d_out, int out_size, void* d_ws, size_t ws_size,
                              hipStream_t stream) {
  (void)in_sizes; (void)n_in; (void)out_size; (void)ws_size;
  const float* X = (const float*)d_in[0];
  const float* Wk[2][3]; const float* Bi[2][3]; const float* Wp[2][3];
  for (int d = 0; d < 2; ++d)
    for (int l = 0; l < 3; ++l) {
      int base = 1 + d * 9 + l * 3;
      Wk[d][l] = (const float*)d_in[base];
      Bi[d][l] = (const float*)d_in[base + 1];
      Wp[d][l] = (const float*)d_in[base + 2];
    }

  char* ws = (char*)d_ws;
  size_t off = 0;
  auto alloc = [&](size_t bytes) -> void* {
    void* p = ws + off;
    off += (bytes + 255) & ~(size_t)255;
    return p;
  };

  _Float16* X16 = (_Float16*)alloc((size_t)T_STEPS * NB * 64 * 2);
  _Float16* WkT[2][3];
  for (int d = 0; d < 2; ++d)
    for (int l = 0; l < 3; ++l)
      WkT[d][l] = (_Float16*)alloc((size_t)NGATE * (l == 0 ? 320 : 512) * 2);
  _Float16* WpT[2][3];
  for (int d = 0; d < 2; ++d)
    for (int l = 0; l < 3; ++l)
      WpT[d][l] = (_Float16*)alloc((size_t)PROJ * HID * 2);
  _Float16* Hbuf = (_Float16*)alloc(6UL * 4 * SL * 2);      // [z][4 slots][640][256]
  float* cst = (float*)alloc(6UL * NB * HID * 4);
  _Float16* gbuf = (_Float16*)alloc(6UL * NB * HID * 2);
  _Float16* embed = (_Float16*)alloc(4UL * SL * 2);         // [d][which][640][256]
  int* bar = (int*)alloc(64 * 4);                           // cnt @0, gen @32

  // ---- prep ----
  {
    size_t tot = (size_t)T_STEPS * NB * 64;
    convX<<<dim3((unsigned)((tot + 255) / 256)), 256, 0, stream>>>(X, X16, tot);
  }
  for (int d = 0; d < 2; ++d)
    for (int l = 0; l < 3; ++l) {
      int Kpad = (l == 0) ? 320 : 512;
      size_t tot = (size_t)NGATE * Kpad;
      conv_wk<<<dim3((unsigned)((tot + 255) / 256)), 256, 0, stream>>>(
          Wk[d][l], WkT[d][l], (l == 0) ? 0 : 1, Kpad, tot);
      size_t totp = (size_t)PROJ * HID;
      conv_wp<<<dim3((unsigned)((totp + 255) / 256)), 256, 0, stream>>>(Wp[d][l], WpT[d][l], totp);
    }
  hipMemsetAsync(Hbuf, 0, 6UL * 4 * SL * 2, stream);        // zero rings (incl. h-init slots)
  hipMemsetAsync(cst, 0, 6UL * NB * HID * 4, stream);       // zero c state
  hipMemsetAsync(bar, 0, 64 * 4, stream);                   // zero barrier (each replay)

  // ---- one persistent launch for all 162 super-steps ----
  PArgs pa{};
  pa.X16 = X16;
  for (int d = 0; d < 2; ++d)
    for (int l = 0; l < 3; ++l) {
      int z = l * 2 + d;
      pa.Wk[z] = WkT[d][l];
      pa.bias[z] = Bi[d][l];
      pa.Wp[z] = WpT[d][l];
    }
  pa.Hbuf = Hbuf;
  pa.cst = cst;
  pa.gbuf = gbuf;
  pa.embed = embed;
  pa.bar = bar;
  persist<<<dim3(720), 256, 0, stream>>>(pa);

  readout<<<dim3(NB), 256, 0, stream>>>(embed, (float*)d_out);
}

// Round 5
// 5509.386 us; speedup vs baseline: 6.7274x; 6.7274x over previous
//
#include <hip/hip_runtime.h>

// BI-LSTM (TF LSTMCell w/ projection), T=160 B=640 F=40 HID=768 PROJ=256, 3 layers x 2 dirs.
// R10: revert to the R6/R8 two-launch structure (best known 5876us; R7 fused-spin 9381us,
// R9 persistent-barrier 37063us -- cross-XCD RELAXED polling reads stale per-XCD L2, and
// per-barrier acquires flush the L2 the kernel boundary keeps warm. Kernel-boundary sync
// is the cheapest coherence mechanism on this chip for this step pattern.)
// NEW in R10: one-iteration REGISTER LOOKAHEAD in both GEMMs' K-loops. Old order issued
// loads(k) right before the barrier, so the ds_write's vmcnt(0) exposed ~300-500cy of L2
// latency EVERY iteration (m233 2-phase stall). New order: ds_write(regs k) -> issue
// loads(k+1) -> MFMA(k): the vmcnt wait for k+1 now sits after a full MFMA phase = hidden.
// LDS stays single-buffered (36.9KB -> 3 blocks/CU, 720-block grid = one round).
// Biggest effect on proj (240 blocks = 1/CU: block serial chain == wall time).

typedef _Float16 h8 __attribute__((ext_vector_type(8)));
typedef float f4 __attribute__((ext_vector_type(4)));

#define T_STEPS 160
#define NB 640
#define HID 768
#define PROJ 256
#define NGATE 3072           // 4*HID

__device__ __forceinline__ float sigm(float x) { return 1.0f / (1.0f + __expf(-x)); }
__device__ __forceinline__ float tanh_fast(float x) { return 2.0f / (1.0f + __expf(-2.0f * x)) - 1.0f; }

struct GateArgs {
  const _Float16* A0[6];   // x-part source (X16 for l=0, prev-layer ring slot otherwise)
  const _Float16* A1[6];   // own h ring slot (h_{t-1} fw / h_{t+1} bw)
  const _Float16* Bw[6];   // WkT, gate-interleaved [3072][Kpad]
  const float*    bias[6];
  float*          cst[6];
  _Float16*       g[6];
  int w0[6];
  int lda0[6];
  int K[6];
  int act[6];
};

struct ProjArgs {
  const _Float16* G[6];    // [640][768] fp16
  const _Float16* Wp[6];   // [256][768] fp16 (B^T)
  _Float16* out[6];        // own ring write slot
  _Float16* out2[6];       // optional embed capture (layer 2, t in {0,159})
  int act[6];
};

// ---------------- gate GEMM: z = [x,h] @ WkT^T, fused bias+gates+c-update -> g ----------------
__global__ __launch_bounds__(256, 3) void gate_step(GateArgs args) {
  const int z = blockIdx.z;
  if (!args.act[z]) return;

  __shared__ __align__(16) char sm[36864];       // As 18KB | Bs 18KB; epilogue overlays zs
  _Float16 (*As)[72] = (_Float16(*)[72])sm;      // [128][72]
  _Float16 (*Bs)[72] = (_Float16(*)[72])(sm + 18432);
  float (*zs)[65] = (float(*)[65])sm;            // [128][65] f32 = 33.3KB

  const _Float16* A0 = args.A0[z];
  const _Float16* A1 = args.A1[z];
  const _Float16* Bw = args.Bw[z];
  const int w0 = args.w0[z], lda0 = args.lda0[z], K = args.K[z];
  const int n0 = blockIdx.x * 128;
  const int m0 = blockIdx.y * 128;
  const int tid = threadIdx.x;
  const int lane = tid & 63;
  const int wv = tid >> 6;         // 0..3
  const int wm = (wv & 1) * 64;    // wave covers rows [wm, wm+64), cols [wn, wn+64)
  const int wn = (wv >> 1) * 64;

  // ---- epilogue-operand prefetch (addresses known from blockIdx/tid alone) ----
  const float* bias = args.bias[z];
  float* cstate = args.cst[z];
  const int uu = tid & 15;
  const int rbase = tid >> 4;
  float cpre[2][8];
  float bpre[2][4];
#pragma unroll
  for (int p = 0; p < 2; ++p) {
    const int u0 = (n0 + p * 64) >> 2;
#pragma unroll
    for (int gg = 0; gg < 4; ++gg)
      bpre[p][gg] = bias[gg * HID + u0 + uu];
#pragma unroll
    for (int it = 0; it < 8; ++it)
      cpre[p][it] = cstate[(size_t)(m0 + it * 16 + rbase) * HID + u0 + uu];
  }

  f4 acc[4][4] = {};

  const int lr = tid >> 3;          // 0..31 (handles rows lr + 32*r)
  const int lkg = (tid & 7) * 8;    // k-group 0,8,..,56

  // ---- prologue: stage k0=0 into registers ----
  h8 av[4], bv[4];
  {
    const int gk = lkg;
    if (gk < w0) {
#pragma unroll
      for (int r = 0; r < 4; ++r)
        av[r] = *(const h8*)(A0 + (size_t)(m0 + lr + 32 * r) * lda0 + gk);
    } else {
#pragma unroll
      for (int r = 0; r < 4; ++r)
        av[r] = *(const h8*)(A1 + (size_t)(m0 + lr + 32 * r) * 256 + (gk - w0));
    }
#pragma unroll
    for (int r = 0; r < 4; ++r)
      bv[r] = *(const h8*)(Bw + (size_t)(n0 + lr + 32 * r) * K + gk);
  }

  for (int k0 = 0; k0 < K; k0 += 64) {
    __syncthreads();                 // prior iter's LDS readers done
#pragma unroll
    for (int r = 0; r < 4; ++r) {    // vmcnt wait here is for regs staged LAST iter (hidden)
      *(h8*)&As[lr + 32 * r][lkg] = av[r];
      *(h8*)&Bs[lr + 32 * r][lkg] = bv[r];
    }
    // issue NEXT iter's loads now; latency hides under this iter's MFMAs
    if (k0 + 64 < K) {
      const int gk = k0 + 64 + lkg;
      if (gk < w0) {
#pragma unroll
        for (int r = 0; r < 4; ++r)
          av[r] = *(const h8*)(A0 + (size_t)(m0 + lr + 32 * r) * lda0 + gk);
      } else {
#pragma unroll
        for (int r = 0; r < 4; ++r)
          av[r] = *(const h8*)(A1 + (size_t)(m0 + lr + 32 * r) * 256 + (gk - w0));
      }
#pragma unroll
      for (int r = 0; r < 4; ++r)
        bv[r] = *(const h8*)(Bw + (size_t)(n0 + lr + 32 * r) * K + gk);
    }
    __syncthreads();
#pragma unroll
    for (int kk = 0; kk < 2; ++kk) {
      const int kq = ((lane >> 4) * 8) + kk * 32;
      h8 bf[4];
#pragma unroll
      for (int j = 0; j < 4; ++j)
        bf[j] = *(const h8*)&Bs[wn + (lane & 15) + 16 * j][kq];
#pragma unroll
      for (int i = 0; i < 4; ++i) {
        h8 af = *(const h8*)&As[wm + (lane & 15) + 16 * i][kq];
#pragma unroll
        for (int j = 0; j < 4; ++j)
          acc[i][j] = __builtin_amdgcn_mfma_f32_16x16x32_f16(af, bf[j], acc[i][j], 0, 0, 0);
      }
    }
  }

  // epilogue: two 64-col passes through zs (16 hidden units each)
  _Float16* gout = args.g[z];
#pragma unroll
  for (int p = 0; p < 2; ++p) {
    __syncthreads();
    if ((wv >> 1) == p) {                   // waves owning n-half p write their acc
#pragma unroll
      for (int mi = 0; mi < 4; ++mi)
#pragma unroll
        for (int ni = 0; ni < 4; ++ni)
#pragma unroll
          for (int r = 0; r < 4; ++r) {
            int row = wm + mi * 16 + ((lane >> 4) << 2) + r;  // C/D: row=(lane>>4)*4+reg
            int col = ni * 16 + (lane & 15);                  //      col=lane&15 (0..63)
            zs[row][col] = acc[mi][ni][r];
          }
    }
    __syncthreads();
    const int u0 = (n0 + p * 64) >> 2;      // first hidden unit of this pass
#pragma unroll
    for (int it = 0; it < 8; ++it) {
      int row = it * 16 + rbase;            // 128 rows x 16 units
      float zi = zs[row][4 * uu + 0] + bpre[p][0];
      float zj = zs[row][4 * uu + 1] + bpre[p][1];
      float zf = zs[row][4 * uu + 2] + bpre[p][2];
      float zo = zs[row][4 * uu + 3] + bpre[p][3];
      size_t co = (size_t)(m0 + row) * HID + u0 + uu;
      float cold = cpre[p][it];
      float cnew = sigm(zf + 1.0f) * cold + sigm(zi) * tanh_fast(zj);  // forget_bias=1.0
      float g = sigm(zo) * tanh_fast(cnew);
      cstate[co] = cnew;
      gout[co] = (_Float16)g;
    }
  }
}

// ---------------- projection GEMM: h = g @ WpT^T ----------------
// 64x64 tile, 256 threads, K=768, register lookahead (1 block/CU: serial chain == wall time).
__global__ __launch_bounds__(256) void proj_step(ProjArgs args) {
  const int z = blockIdx.z;
  if (!args.act[z]) return;

  __shared__ __align__(16) _Float16 As[64][72];
  __shared__ __align__(16) _Float16 Bs[64][72];

  const _Float16* A = args.G[z];
  const _Float16* B = args.Wp[z];
  const int n0 = blockIdx.x * 64;
  const int m0 = blockIdx.y * 64;
  const int tid = threadIdx.x;
  const int lane = tid & 63;
  const int wv = tid >> 6;
  const int wm = (wv & 1) * 32;
  const int wn = (wv >> 1) * 32;

  f4 acc[2][2] = {};
  const int lr = tid >> 3;
  const int lkg = (tid & 7) * 8;

  // prologue: stage k0=0
  h8 av0 = *(const h8*)(A + (size_t)(m0 + lr) * HID + lkg);
  h8 av1 = *(const h8*)(A + (size_t)(m0 + lr + 32) * HID + lkg);
  h8 bv0 = *(const h8*)(B + (size_t)(n0 + lr) * HID + lkg);
  h8 bv1 = *(const h8*)(B + (size_t)(n0 + lr + 32) * HID + lkg);

  for (int k0 = 0; k0 < HID; k0 += 64) {
    __syncthreads();
    *(h8*)&As[lr][lkg] = av0;
    *(h8*)&As[lr + 32][lkg] = av1;
    *(h8*)&Bs[lr][lkg] = bv0;
    *(h8*)&Bs[lr + 32][lkg] = bv1;
    if (k0 + 64 < HID) {
      const int gk = k0 + 64 + lkg;
      av0 = *(const h8*)(A + (size_t)(m0 + lr) * HID + gk);
      av1 = *(const h8*)(A + (size_t)(m0 + lr + 32) * HID + gk);
      bv0 = *(const h8*)(B + (size_t)(n0 + lr) * HID + gk);
      bv1 = *(const h8*)(B + (size_t)(n0 + lr + 32) * HID + gk);
    }
    __syncthreads();
    const int mr = wm + (lane & 15);
    const int nr = wn + (lane & 15);
#pragma unroll
    for (int kk = 0; kk < 2; ++kk) {
      const int kq = ((lane >> 4) * 8) + kk * 32;
      h8 a0 = *(const h8*)&As[mr][kq];
      h8 a1 = *(const h8*)&As[mr + 16][kq];
      h8 b0 = *(const h8*)&Bs[nr][kq];
      h8 b1 = *(const h8*)&Bs[nr + 16][kq];
      acc[0][0] = __builtin_amdgcn_mfma_f32_16x16x32_f16(a0, b0, acc[0][0], 0, 0, 0);
      acc[0][1] = __builtin_amdgcn_mfma_f32_16x16x32_f16(a0, b1, acc[0][1], 0, 0, 0);
      acc[1][0] = __builtin_amdgcn_mfma_f32_16x16x32_f16(a1, b0, acc[1][0], 0, 0, 0);
      acc[1][1] = __builtin_amdgcn_mfma_f32_16x16x32_f16(a1, b1, acc[1][1], 0, 0, 0);
    }
  }

  _Float16* outp = args.out[z];
  _Float16* out2 = args.out2[z];
#pragma unroll
  for (int mi = 0; mi < 2; ++mi)
#pragma unroll
    for (int ni = 0; ni < 2; ++ni)
#pragma unroll
      for (int r = 0; r < 4; ++r) {
        int row = wm + mi * 16 + ((lane >> 4) << 2) + r;
        int col = wn + ni * 16 + (lane & 15);
        _Float16 v = (_Float16)acc[mi][ni][r];
        size_t o = (size_t)(m0 + row) * PROJ + (n0 + col);
        outp[o] = v;
        if (out2) out2[o] = v;
      }
}

// ---------------- prep kernels ----------------
__global__ void convX(const float* __restrict__ X, _Float16* __restrict__ X16, size_t total) {
  size_t i = (size_t)blockIdx.x * 256 + threadIdx.x;
  if (i >= total) return;
  int p = (int)(i & 63);
  size_t tb = i >> 6;
  float v = (p < 40) ? X[tb * 40 + p] : 0.0f;
  X16[i] = (_Float16)v;
}

// Wk fp32 [Kin+256, 3072] -> WkT fp16 [3072][Kpad], gate-interleaved rows n'=4u+g,
// layer0 k-map: k<40 -> Wk[k]; 40..63 -> 0; 64..319 -> Wk[k-24]
__global__ void conv_wk(const float* __restrict__ Wk, _Float16* __restrict__ out,
                        int mode, int Kpad, size_t total) {
  size_t i = (size_t)blockIdx.x * 256 + threadIdx.x;
  if (i >= total) return;
  int k = (int)(i % Kpad);
  int n = (int)(i / Kpad);
  int u = n >> 2, g = n & 3;
  int col = g * HID + u;
  float v;
  if (mode == 0) {
    if (k < 40)      v = Wk[(size_t)k * NGATE + col];
    else if (k < 64) v = 0.0f;
    else             v = Wk[(size_t)(k - 24) * NGATE + col];
  } else {
    v = Wk[(size_t)k * NGATE + col];
  }
  out[i] = (_Float16)v;
}

__global__ void conv_wp(const float* __restrict__ Wp, _Float16* __restrict__ out, size_t total) {
  size_t i = (size_t)blockIdx.x * 256 + threadIdx.x;
  if (i >= total) return;
  int k = (int)(i % HID);
  int c = (int)(i / HID);
  out[i] = (_Float16)Wp[(size_t)k * PROJ + c];
}

// ---------------- readout ----------------
__global__ __launch_bounds__(256) void readout(const _Float16* __restrict__ E, float* __restrict__ out) {
  const size_t SL = (size_t)NB * PROJ;
  int b = blockIdx.x, tid = threadIdx.x;
  float v[2];
  float ss = 0.0f;
#pragma unroll
  for (int i = 0; i < 2; ++i) {
    int j = tid + i * 256;
    int d = j >> 8, c = j & 255;
    const _Float16* base = E + (size_t)d * 2 * SL;
    float a = (float)base[(size_t)b * PROJ + c];
    float zv = (float)base[SL + (size_t)b * PROJ + c];
    v[i] = 0.5f * (a + zv);
    ss += v[i] * v[i];
  }
#pragma unroll
  for (int off = 32; off; off >>= 1) ss += __shfl_down(ss, off);
  __shared__ float ps[4];
  if ((tid & 63) == 0) ps[tid >> 6] = ss;
  __syncthreads();
  float tot = ps[0] + ps[1] + ps[2] + ps[3];
  float nrm = rsqrtf(fmaxf(tot, 1e-12f));
  out[(size_t)b * 512 + tid] = v[0] * nrm;
  out[(size_t)b * 512 + tid + 256] = v[1] * nrm;
}

extern "C" void kernel_launch(void* const* d_in, const int* in_sizes, int n_in,
                              void* d_out, int out_size, void* d_ws, size_t ws_size,
                              hipStream_t stream) {
  (void)in_sizes; (void)n_in; (void)out_size; (void)ws_size;
  const float* X = (const float*)d_in[0];
  const float* Wk[2][3]; const float* Bi[2][3]; const float* Wp[2][3];
  for (int d = 0; d < 2; ++d)
    for (int l = 0; l < 3; ++l) {
      int base = 1 + d * 9 + l * 3;
      Wk[d][l] = (const float*)d_in[base];
      Bi[d][l] = (const float*)d_in[base + 1];
      Wp[d][l] = (const float*)d_in[base + 2];
    }

  char* ws = (char*)d_ws;
  size_t off = 0;
  auto alloc = [&](size_t bytes) -> void* {
    void* p = ws + off;
    off += (bytes + 255) & ~(size_t)255;
    return p;
  };

  const size_t SL = (size_t)NB * PROJ;    // halves per time-slot

  _Float16* X16 = (_Float16*)alloc((size_t)T_STEPS * NB * 64 * 2);
  _Float16* WkT[2][3];
  for (int d = 0; d < 2; ++d)
    for (int l = 0; l < 3; ++l)
      WkT[d][l] = (_Float16*)alloc((size_t)NGATE * (l == 0 ? 320 : 512) * 2);
  _Float16* WpT[2][3];
  for (int d = 0; d < 2; ++d)
    for (int l = 0; l < 3; ++l)
      WpT[d][l] = (_Float16*)alloc((size_t)PROJ * HID * 2);
  _Float16* Hbuf = (_Float16*)alloc(6UL * 4 * SL * 2);      // [l*2+d][4 slots][640][256]
  float* cst = (float*)alloc(6UL * NB * HID * 4);
  _Float16* gbuf = (_Float16*)alloc(6UL * NB * HID * 2);
  _Float16* embed = (_Float16*)alloc(4UL * SL * 2);         // [d][which][640][256]

  auto Hslot = [&](int l, int d, int slot) -> _Float16* {
    return Hbuf + (((size_t)(l * 2 + d) * 4) + slot) * SL;
  };

  // ---- prep ----
  {
    size_t tot = (size_t)T_STEPS * NB * 64;
    convX<<<dim3((unsigned)((tot + 255) / 256)), 256, 0, stream>>>(X, X16, tot);
  }
  for (int d = 0; d < 2; ++d)
    for (int l = 0; l < 3; ++l) {
      int Kpad = (l == 0) ? 320 : 512;
      size_t tot = (size_t)NGATE * Kpad;
      conv_wk<<<dim3((unsigned)((tot + 255) / 256)), 256, 0, stream>>>(
          Wk[d][l], WkT[d][l], (l == 0) ? 0 : 1, Kpad, tot);
      size_t totp = (size_t)PROJ * HID;
      conv_wp<<<dim3((unsigned)((totp + 255) / 256)), 256, 0, stream>>>(Wp[d][l], WpT[d][l], totp);
    }
  hipMemsetAsync(Hbuf, 0, 6UL * 4 * SL * 2, stream);        // zero rings (incl. h-init slots)
  hipMemsetAsync(cst, 0, 6UL * NB * HID * 4, stream);       // zero c state

  // ---- pipelined super-steps ----
  for (int s = 0; s <= 161; ++s) {
    GateArgs ga{};
    ProjArgs pa{};
    for (int l = 0; l < 3; ++l)
      for (int d = 0; d < 2; ++d) {
        int z = l * 2 + d;
        int t = s - l;                        // progress of layer l
        if (t < 0 || t > 159) { ga.act[z] = 0; pa.act[z] = 0; continue; }
        int tt = (d == 0) ? t : 159 - t;      // actual time index
        ga.act[z] = 1; pa.act[z] = 1;
        if (l == 0) {
          ga.A0[z] = X16 + (size_t)tt * NB * 64;
          ga.w0[z] = 64; ga.lda0[z] = 64; ga.K[z] = 320;
        } else {
          ga.A0[z] = Hslot(l - 1, d, (tt + 1) & 3);   // prev-layer output at time tt
          ga.w0[z] = 256; ga.lda0[z] = 256; ga.K[z] = 512;
        }
        int rdslot = (d == 0) ? (tt & 3) : ((tt + 2) & 3);
        ga.A1[z] = Hslot(l, d, rdslot);
        ga.Bw[z] = WkT[d][l];
        ga.bias[z] = Bi[d][l];
        ga.cst[z] = cst + (size_t)z * NB * HID;
        ga.g[z] = gbuf + (size_t)z * NB * HID;

        pa.G[z] = gbuf + (size_t)z * NB * HID;
        pa.Wp[z] = WpT[d][l];
        pa.out[z] = Hslot(l, d, (tt + 1) & 3);
        pa.out2[z] = nullptr;
        if (l == 2 && (tt == 0 || tt == 159))
          pa.out2[z] = embed + ((size_t)d * 2 + (tt == 0 ? 0 : 1)) * SL;
      }
    gate_step<<<dim3(24, 5, 6), 256, 0, stream>>>(ga);
    proj_step<<<dim3(4, 10, 6), 256, 0, stream>>>(pa);
  }

  readout<<<dim3(NB), 256, 0, stream>>>(embed, (float*)d_out);
}